// Round 4
// baseline (885.416 us; speedup 1.0000x reference)
//
#include <hip/hip_runtime.h>

#define DM 128
#define NHEADS 8

typedef __attribute__((ext_vector_type(8))) __bf16 bf16x8;
typedef __attribute__((ext_vector_type(4))) float f32x4;

__device__ inline unsigned short f2bf(float f) {
    unsigned u = __float_as_uint(f);
    u += 0x7FFFu + ((u >> 16) & 1u);
    return (unsigned short)(u >> 16);
}

// ---------------- LDS layout (bytes) ----------------
// K   [64][136] bf16 : 17408  (token-major; rows >= 16*mtiles stay zero)
// Vt  [128][72] bf16 : 18432  (dim-major: [dim][token]; pads zeroed)
// XB  [64][136] bf16 : 17408  (x input, later attn_out)
// Q   [64][136] bf16 : 17408  (aliased by P [64][72] after preload)
#define K_OFF   0
#define VT_OFF  17408
#define XB_OFF  35840
#define Q_OFF   53248
#define P_OFF   53248
#define SMEM_BYTES 70656

// ---------- prep: weight->bf16 conversion (blocks 0..63) + offset scan (block 64) ----------
__global__ void prep(const int* __restrict__ agents, int B,
                     const float* __restrict__ wqkv, const float* __restrict__ wout,
                     int* __restrict__ offs,
                     unsigned short* __restrict__ wqkv_bf,
                     unsigned short* __restrict__ wout_bf) {
    if (blockIdx.x < 64) {
        int idx = (blockIdx.x * 256 + threadIdx.x) * 4;   // 0..65532
        if (idx < 49152) {
            float4 v = *(const float4*)(wqkv + idx);
            ushort4 o;
            o.x = f2bf(v.x); o.y = f2bf(v.y); o.z = f2bf(v.z); o.w = f2bf(v.w);
            *(ushort4*)(wqkv_bf + idx) = o;
        } else {
            int j = idx - 49152;
            float4 v = *(const float4*)(wout + j);
            ushort4 o;
            o.x = f2bf(v.x); o.y = f2bf(v.y); o.z = f2bf(v.z); o.w = f2bf(v.w);
            *(ushort4*)(wout_bf + j) = o;
        }
    } else {
        __shared__ int part[256];
        const int tid = threadIdx.x;
        const int per = (B + 255) >> 8;
        const int base = tid * per;
        int s = 0;
        for (int i = 0; i < per; ++i) {
            int idx = base + i;
            if (idx < B) s += agents[idx];
        }
        part[tid] = s;
        __syncthreads();
        for (int off = 1; off < 256; off <<= 1) {
            int v = (tid >= off) ? part[tid - off] : 0;
            __syncthreads();
            part[tid] += v;
            __syncthreads();
        }
        int run = (tid == 0) ? 0 : part[tid - 1];
        for (int i = 0; i < per; ++i) {
            int idx = base + i;
            if (idx < B) { offs[idx] = run; run += agents[idx]; }
        }
    }
}

// ---------------- fused MHSA: 1 block/sample, 4 waves, register-resident weights ----------------
__launch_bounds__(256, 2)
__global__ void mhsa(const float* __restrict__ x,
                     const unsigned short* __restrict__ wqkvb,
                     const float* __restrict__ bqkv,
                     const unsigned short* __restrict__ woutb,
                     const float* __restrict__ bout,
                     const int* __restrict__ agents,
                     const int* __restrict__ offs,
                     float* __restrict__ out) {
    __shared__ __align__(16) char smem[SMEM_BYTES];
    unsigned short* Kb = (unsigned short*)(smem + K_OFF);
    unsigned short* Vt = (unsigned short*)(smem + VT_OFF);
    unsigned short* XB = (unsigned short*)(smem + XB_OFF);
    unsigned short* Qb = (unsigned short*)(smem + Q_OFF);
    unsigned short* Pb = (unsigned short*)(smem + P_OFF);

    const int b = blockIdx.x;
    const int n = agents[b];
    const int base = offs[b];
    const int tid = threadIdx.x;
    const int wave = tid >> 6, lane = tid & 63;
    const int quad = lane >> 4, l16 = lane & 15;
    const int m0w = wave * 16;
    const int mtiles = (n + 15) >> 4;      // 1..4 active M-tiles
    const int nks = (n + 31) >> 5;         // 1..2 active 32-key groups

    // ---- Prefetch this wave's QKV weight strip (96 cols) into registers.
    // Issued before Phase A so the ~200cyc L2 latency overlaps the x load.
    bf16x8 wq[6][4];
    float bq[6];
    #pragma unroll
    for (int cg = 0; cg < 6; ++cg) {
        const int col = wave * 96 + cg * 16 + l16;
        #pragma unroll
        for (int ks = 0; ks < 4; ++ks)
            wq[cg][ks] = *(const bf16x8*)(wqkvb + col * DM + ks * 32 + quad * 8);
        bq[cg] = bqkv[col];
    }

    // ---- Phase A: zero K+Vt span (NaN-safety for pad/unwritten B-fragment
    // reads multiplied by A=0), fill XB rows (zero beyond n) ----
    for (int f = tid; f < 2240; f += 256)            // K(1088) + Vt(1152) uint4
        ((uint4*)smem)[f] = make_uint4(0u, 0u, 0u, 0u);
    for (int f = tid; f < 2048; f += 256) {
        int t = f >> 5, c = f & 31;
        ushort4 o = make_ushort4(0, 0, 0, 0);
        if (t < n) {
            float4 v = ((const float4*)(x + (size_t)(base + t) * DM))[c];
            o.x = f2bf(v.x); o.y = f2bf(v.y); o.z = f2bf(v.z); o.w = f2bf(v.w);
        }
        *(ushort4*)(XB + t * 136 + c * 4) = o;
    }
    __syncthreads();

    // ---- Phase B: qkv = x @ Wqkv^T + b. Wave owns 96 cols; loops M-tiles.
    // No barriers: XB read-only, scatter regions disjoint per (wave,cg). ----
    #pragma unroll
    for (int cg = 0; cg < 6; ++cg) {
        const int col = wave * 96 + cg * 16 + l16;
        for (int mt = 0; mt < mtiles; ++mt) {
            const int m0 = mt * 16;
            f32x4 acc = {0.f, 0.f, 0.f, 0.f};
            #pragma unroll
            for (int ks = 0; ks < 4; ++ks) {
                bf16x8 a = *(const bf16x8*)(XB + (m0 + l16) * 136 + ks * 32 + quad * 8);
                acc = __builtin_amdgcn_mfma_f32_16x16x32_bf16(a, wq[cg][ks], acc, 0, 0, 0);
            }
            if (col < 128) {                       // Q (waves 0,1)
                #pragma unroll
                for (int r = 0; r < 4; ++r)
                    Qb[(m0 + quad * 4 + r) * 136 + col] = f2bf(acc[r] + bq[cg]);
            } else if (col < 256) {                // K (waves 1,2)
                #pragma unroll
                for (int r = 0; r < 4; ++r)
                    Kb[(m0 + quad * 4 + r) * 136 + (col - 128)] = f2bf(acc[r] + bq[cg]);
            } else {                               // V transposed (waves 2,3): 4 consecutive tokens
                ushort4 o;
                o.x = f2bf(acc[0] + bq[cg]); o.y = f2bf(acc[1] + bq[cg]);
                o.z = f2bf(acc[2] + bq[cg]); o.w = f2bf(acc[3] + bq[cg]);
                *(ushort4*)(Vt + (col - 256) * 72 + m0 + quad * 4) = o;
            }
        }
    }
    __syncthreads();

    // ---- Q preload into registers (A-layout, head_dim 16 zero-padded to K=32) ----
    bf16x8 qf[NHEADS];
    #pragma unroll
    for (int h = 0; h < NHEADS; ++h) qf[h] = (bf16x8)(__bf16)0.0f;
    const bool active = (m0w < n);
    if (active) {
        #pragma unroll
        for (int h = 0; h < NHEADS; ++h)
            if (quad < 2)
                qf[h] = *(const bf16x8*)(Qb + (m0w + l16) * 136 + h * 16 + quad * 8);
    }
    __syncthreads();   // P aliases Q: all waves must finish Q reads first

    // ---- Prefetch Phase-D weight strip (32 cols): latency hides under Phase C ----
    bf16x8 wo[2][4];
    float bo2[2];
    #pragma unroll
    for (int cg = 0; cg < 2; ++cg) {
        const int colD = wave * 32 + cg * 16 + l16;
        #pragma unroll
        for (int ks = 0; ks < 4; ++ks)
            wo[cg][ks] = *(const bf16x8*)(woutb + colD * DM + ks * 32 + quad * 8);
        bo2[cg] = bout[colD];
    }

    // ---- Phase C: attention; wave-private, no barriers; kt/ks bounded by n ----
    if (active) {
        for (int h = 0; h < NHEADS; ++h) {
            f32x4 sc[4];
            #pragma unroll
            for (int kt = 0; kt < 4; ++kt) {
                if (kt < 2 * nks) {
                    bf16x8 bb = *(const bf16x8*)(Kb + (kt * 16 + l16) * 136 + h * 16 + quad * 8);
                    sc[kt] = __builtin_amdgcn_mfma_f32_16x16x32_bf16(qf[h], bb,
                              (f32x4){0.f, 0.f, 0.f, 0.f}, 0, 0, 0);
                }
            }
            #pragma unroll
            for (int r = 0; r < 4; ++r) {
                float pr[4];
                float mm = -1e30f;
                #pragma unroll
                for (int kt = 0; kt < 4; ++kt) {
                    float v = -1e30f;
                    if (kt < 2 * nks) {
                        int key = kt * 16 + l16;
                        v = (key < n) ? sc[kt][r] * 0.25f : -1e30f;   // scale = 1/sqrt(16)
                    }
                    pr[kt] = v;
                    mm = fmaxf(mm, v);
                }
                mm = fmaxf(mm, __shfl_xor(mm, 1));
                mm = fmaxf(mm, __shfl_xor(mm, 2));
                mm = fmaxf(mm, __shfl_xor(mm, 4));
                mm = fmaxf(mm, __shfl_xor(mm, 8));
                float ll = 0.f;
                #pragma unroll
                for (int kt = 0; kt < 4; ++kt) {
                    if (kt < 2 * nks) {
                        float e = __expf(pr[kt] - mm);
                        pr[kt] = e;
                        ll += e;
                    }
                }
                ll += __shfl_xor(ll, 1);
                ll += __shfl_xor(ll, 2);
                ll += __shfl_xor(ll, 4);
                ll += __shfl_xor(ll, 8);
                float inv = 1.0f / ll;
                #pragma unroll
                for (int kt = 0; kt < 4; ++kt)
                    if (kt < 2 * nks)
                        Pb[(m0w + quad * 4 + r) * 72 + kt * 16 + l16] = f2bf(pr[kt] * inv);
            }
            f32x4 o = {0.f, 0.f, 0.f, 0.f};
            #pragma unroll
            for (int ks = 0; ks < 2; ++ks) {
                if (ks < nks) {
                    bf16x8 a = *(const bf16x8*)(Pb + (m0w + l16) * 72 + ks * 32 + quad * 8);
                    bf16x8 bb = *(const bf16x8*)(Vt + (h * 16 + l16) * 72 + ks * 32 + quad * 8);
                    o = __builtin_amdgcn_mfma_f32_16x16x32_bf16(a, bb, o, 0, 0, 0);
                }
            }
            #pragma unroll
            for (int r = 0; r < 4; ++r)
                XB[(m0w + quad * 4 + r) * 136 + h * 16 + l16] = f2bf(o[r]);
        }
    }
    __syncthreads();

    // ---- Phase D: out = attn_out @ Wout^T + b. Wave owns 32 cols; no barriers. ----
    #pragma unroll
    for (int cg = 0; cg < 2; ++cg) {
        const int colD = wave * 32 + cg * 16 + l16;
        for (int mt = 0; mt < mtiles; ++mt) {
            f32x4 acc = {0.f, 0.f, 0.f, 0.f};
            #pragma unroll
            for (int ks = 0; ks < 4; ++ks) {
                bf16x8 a = *(const bf16x8*)(XB + (mt * 16 + l16) * 136 + ks * 32 + quad * 8);
                acc = __builtin_amdgcn_mfma_f32_16x16x32_bf16(a, wo[cg][ks], acc, 0, 0, 0);
            }
            #pragma unroll
            for (int r = 0; r < 4; ++r) {
                int row = mt * 16 + quad * 4 + r;
                if (row < n)
                    out[(size_t)(base + row) * DM + colD] = acc[r] + bo2[cg];
            }
        }
    }
}

extern "C" void kernel_launch(void* const* d_in, const int* in_sizes, int n_in,
                              void* d_out, int out_size, void* d_ws, size_t ws_size,
                              hipStream_t stream) {
    const float* att_in     = (const float*)d_in[0];
    const float* in_proj_w  = (const float*)d_in[1];
    const float* in_proj_b  = (const float*)d_in[2];
    const float* out_proj_w = (const float*)d_in[3];
    const float* out_proj_b = (const float*)d_in[4];
    const int*   agents     = (const int*)d_in[5];
    const int B = in_sizes[5];

    // ws layout: offs [B*4 B] | wqkv_bf16 [98304 B] | wout_bf16 [32768 B]
    int* offs = (int*)d_ws;
    unsigned short* wqkv_bf = (unsigned short*)((char*)d_ws + 8192);
    unsigned short* wout_bf = (unsigned short*)((char*)d_ws + 8192 + 98304);

    hipLaunchKernelGGL(prep, dim3(65), dim3(256), 0, stream,
                       agents, B, in_proj_w, out_proj_w, offs, wqkv_bf, wout_bf);
    hipLaunchKernelGGL(mhsa, dim3(B), dim3(256), 0, stream,
                       att_in, wqkv_bf, in_proj_b, wout_bf, out_proj_b,
                       agents, offs, (float*)d_out);
}

// Round 6
// 223.316 us; speedup vs baseline: 3.9649x; 3.9649x over previous
//
#include <hip/hip_runtime.h>

#define DM 128
#define NHEADS 8

typedef __attribute__((ext_vector_type(8))) __bf16 bf16x8;
typedef __attribute__((ext_vector_type(4))) float f32x4;

__device__ inline unsigned short f2bf(float f) {
    unsigned u = __float_as_uint(f);
    u += 0x7FFFu + ((u >> 16) & 1u);
    return (unsigned short)(u >> 16);
}

// ---------- prep: weight->bf16 conversion (blocks 0..63) + offset scan (block 64) ----------
__global__ void prep(const int* __restrict__ agents, int B,
                     const float* __restrict__ wqkv, const float* __restrict__ wout,
                     int* __restrict__ offs,
                     unsigned short* __restrict__ wqkv_bf,
                     unsigned short* __restrict__ wout_bf) {
    if (blockIdx.x < 64) {
        int idx = (blockIdx.x * 256 + threadIdx.x) * 4;   // 0..65532
        if (idx < 49152) {
            float4 v = *(const float4*)(wqkv + idx);
            ushort4 o;
            o.x = f2bf(v.x); o.y = f2bf(v.y); o.z = f2bf(v.z); o.w = f2bf(v.w);
            *(ushort4*)(wqkv_bf + idx) = o;
        } else {
            int j = idx - 49152;
            float4 v = *(const float4*)(wout + j);
            ushort4 o;
            o.x = f2bf(v.x); o.y = f2bf(v.y); o.z = f2bf(v.z); o.w = f2bf(v.w);
            *(ushort4*)(wout_bf + j) = o;
        }
    } else {
        __shared__ int part[256];
        const int tid = threadIdx.x;
        const int per = (B + 255) >> 8;
        const int base = tid * per;
        int s = 0;
        for (int i = 0; i < per; ++i) {
            int idx = base + i;
            if (idx < B) s += agents[idx];
        }
        part[tid] = s;
        __syncthreads();
        for (int off = 1; off < 256; off <<= 1) {
            int v = (tid >= off) ? part[tid - off] : 0;
            __syncthreads();
            part[tid] += v;
            __syncthreads();
        }
        int run = (tid == 0) ? 0 : part[tid - 1];
        for (int i = 0; i < per; ++i) {
            int idx = base + i;
            if (idx < B) { offs[idx] = run; run += agents[idx]; }
        }
    }
}

// ---------- kernel 1: qkv GEMM  [M,128] x [384,128]^T -> Q(ws bf16), K|V(d_out bf16) ----------
__launch_bounds__(256, 4)
__global__ void qkv_gemm(const float* __restrict__ x,
                         const unsigned short* __restrict__ wqkvb,
                         const float* __restrict__ bqkv,
                         unsigned short* __restrict__ qws,   // [M][128] bf16
                         unsigned short* __restrict__ kv,    // [M][256] bf16 (K|V)
                         int M) {
    __shared__ __align__(16) unsigned short As[64 * 136];
    __shared__ __align__(16) unsigned short Bs[64 * 136];
    const int m0 = blockIdx.x * 64;
    const int nc0 = blockIdx.y * 64;
    const int tid = threadIdx.x;

    for (int f = tid; f < 2048; f += 256) {          // A: 64 rows x 128 fp32 -> bf16 (zero pad)
        int t = f >> 5, c = f & 31;
        ushort4 o = make_ushort4(0, 0, 0, 0);
        if (m0 + t < M) {
            float4 v = ((const float4*)(x + (size_t)(m0 + t) * DM))[c];
            o.x = f2bf(v.x); o.y = f2bf(v.y); o.z = f2bf(v.z); o.w = f2bf(v.w);
        }
        *(ushort4*)&As[t * 136 + c * 4] = o;
    }
    for (int f = tid; f < 1024; f += 256) {          // B: 64 weight rows x 128 bf16 (16 uint4/row)
        int r = f >> 4, c = f & 15;
        *(uint4*)&Bs[r * 136 + c * 8] = *(const uint4*)(wqkvb + (size_t)(nc0 + r) * DM + c * 8);
    }
    __syncthreads();

    const int wave = tid >> 6, lane = tid & 63, quad = lane >> 4, l16 = lane & 15;
    const int mr = wave * 16;
    #pragma unroll
    for (int ct = 0; ct < 4; ++ct) {
        f32x4 acc = {0.f, 0.f, 0.f, 0.f};
        #pragma unroll
        for (int ks = 0; ks < 4; ++ks) {
            bf16x8 a = *(const bf16x8*)&As[(mr + l16) * 136 + ks * 32 + quad * 8];
            bf16x8 bb = *(const bf16x8*)&Bs[(ct * 16 + l16) * 136 + ks * 32 + quad * 8];
            acc = __builtin_amdgcn_mfma_f32_16x16x32_bf16(a, bb, acc, 0, 0, 0);
        }
        const int gc = nc0 + ct * 16 + l16;
        const float bias = bqkv[gc];
        #pragma unroll
        for (int r = 0; r < 4; ++r) {
            int row = m0 + mr + quad * 4 + r;
            if (row < M) {
                unsigned short v = f2bf(acc[r] + bias);
                if (gc < 128)       qws[(size_t)row * 128 + gc] = v;
                else if (gc < 256)  kv[(size_t)row * 256 + (gc - 128)] = v;
                else                kv[(size_t)row * 256 + 128 + (gc - 256)] = v;
            }
        }
    }
}

// ---------- kernel 2: attention. 1 block/sample, 8 waves (1/head), LDS-staged Q/K/Vt ----------
// LDS: Qs[64][136] | Ks[64][136] | Vt[128][72] | Ps[8][16][72]  = 71680 B -> 2 blocks/CU
#define QS_OFF 0
#define KS_OFF 17408
#define VT2_OFF 34816
#define PS_OFF 53248
#define SMEM2 71680

__launch_bounds__(512, 4)
__global__ void attn(unsigned short* __restrict__ qa,       // in: Q [M][128]; out: attn (same buf)
                     const unsigned short* __restrict__ kv, // [M][256] K|V
                     const int* __restrict__ agents,
                     const int* __restrict__ offs) {
    __shared__ __align__(16) char smem[SMEM2];
    unsigned short* Qs = (unsigned short*)(smem + QS_OFF);
    unsigned short* Ks = (unsigned short*)(smem + KS_OFF);
    unsigned short* Vt = (unsigned short*)(smem + VT2_OFF);
    unsigned short* Ps = (unsigned short*)(smem + PS_OFF);

    const int s = blockIdx.x;
    const int n = agents[s];
    const int base = offs[s];
    const int tid = threadIdx.x;
    const int wave = tid >> 6, lane = tid & 63, quad = lane >> 4, l16 = lane & 15;
    const int h = wave;                      // one wave per head
    const int nkt = (n + 15) >> 4;           // 16-key tiles
    const int nks = (n + 31) >> 5;           // 32-key groups

    // zero ENTIRE smem: stale rows >= n in Qs/Ks/Vt and Ps pads must be finite
    // (R2/R5 lesson: NaN * 0 = NaN inside MFMA; half-staged rows poison valid heads)
    for (int f = tid; f < 4480; f += 512)
        ((uint4*)smem)[f] = make_uint4(0u, 0u, 0u, 0u);
    __syncthreads();

    // stage full Q, K rows (128 bf16 = 16 uint4 each), V transposed (scalar u16)
    for (int f = tid; f < n * 16; f += 512) {
        int t = f >> 4, c = f & 15;
        *(uint4*)&Qs[t * 136 + c * 8] = *(const uint4*)(qa + (size_t)(base + t) * 128 + c * 8);
        *(uint4*)&Ks[t * 136 + c * 8] = *(const uint4*)(kv + (size_t)(base + t) * 256 + c * 8);
    }
    for (int f = tid; f < n * 32; f += 512) {
        int t = f >> 5, c4 = f & 31;
        ushort4 vv = *(const ushort4*)(kv + (size_t)(base + t) * 256 + 128 + c4 * 4);
        Vt[(c4 * 4 + 0) * 72 + t] = vv.x;
        Vt[(c4 * 4 + 1) * 72 + t] = vv.y;
        Vt[(c4 * 4 + 2) * 72 + t] = vv.z;
        Vt[(c4 * 4 + 3) * 72 + t] = vv.w;
    }
    __syncthreads();   // after this, the global Q rows of this sample are free to overwrite

    unsigned short* Pw = Ps + wave * 16 * 72;
    for (int mt = 0; mt < nkt; ++mt) {       // query tiles (same count as key tiles)
        bf16x8 qf = (bf16x8)(__bf16)0.0f;
        if (quad < 2)
            qf = *(const bf16x8*)&Qs[(mt * 16 + l16) * 136 + h * 16 + quad * 8];
        f32x4 sc[4];
        #pragma unroll
        for (int kt = 0; kt < 4; ++kt) {
            if (kt < nkt) {
                bf16x8 bb = *(const bf16x8*)&Ks[(kt * 16 + l16) * 136 + h * 16 + quad * 8];
                sc[kt] = __builtin_amdgcn_mfma_f32_16x16x32_bf16(qf, bb,
                          (f32x4){0.f, 0.f, 0.f, 0.f}, 0, 0, 0);
            }
        }
        #pragma unroll
        for (int r = 0; r < 4; ++r) {
            float pr[4];
            float mm = -1e30f;
            #pragma unroll
            for (int kt = 0; kt < 4; ++kt) {
                float v = -1e30f;
                if (kt < nkt) {
                    int key = kt * 16 + l16;
                    v = (key < n) ? sc[kt][r] * 0.25f : -1e30f;   // scale = 1/sqrt(16)
                }
                pr[kt] = v;
                mm = fmaxf(mm, v);
            }
            mm = fmaxf(mm, __shfl_xor(mm, 1));
            mm = fmaxf(mm, __shfl_xor(mm, 2));
            mm = fmaxf(mm, __shfl_xor(mm, 4));
            mm = fmaxf(mm, __shfl_xor(mm, 8));
            float ll = 0.f;
            #pragma unroll
            for (int kt = 0; kt < 4; ++kt) {
                if (kt < nkt) {
                    float e = __expf(pr[kt] - mm);
                    pr[kt] = e;
                    ll += e;
                }
            }
            ll += __shfl_xor(ll, 1);
            ll += __shfl_xor(ll, 2);
            ll += __shfl_xor(ll, 4);
            ll += __shfl_xor(ll, 8);
            float inv = 1.0f / ll;
            #pragma unroll
            for (int kt = 0; kt < 4; ++kt)
                if (kt < nkt)
                    Pw[(quad * 4 + r) * 72 + kt * 16 + l16] = f2bf(pr[kt] * inv);
        }
        // PV
        f32x4 o = {0.f, 0.f, 0.f, 0.f};
        #pragma unroll
        for (int ks = 0; ks < 2; ++ks) {
            if (ks < nks) {
                bf16x8 a = *(const bf16x8*)&Pw[l16 * 72 + ks * 32 + quad * 8];
                bf16x8 bb = *(const bf16x8*)&Vt[(h * 16 + l16) * 72 + ks * 32 + quad * 8];
                o = __builtin_amdgcn_mfma_f32_16x16x32_bf16(a, bb, o, 0, 0, 0);
            }
        }
        #pragma unroll
        for (int r = 0; r < 4; ++r) {
            int row = mt * 16 + quad * 4 + r;
            if (row < n)
                qa[(size_t)(base + row) * 128 + h * 16 + l16] = f2bf(o[r]);
        }
    }
}

// ---------- kernel 3: out-proj GEMM  attn[M,128] x Wout[128,128]^T + b -> d_out fp32 ----------
__launch_bounds__(256, 3)
__global__ void oproj(const unsigned short* __restrict__ attn_b,  // [M][128] bf16 (ws)
                      const unsigned short* __restrict__ woutb,
                      const float* __restrict__ bout,
                      float* __restrict__ out, int M) {
    __shared__ __align__(16) unsigned short Ws[128 * 136];   // 34816 B
    __shared__ __align__(16) unsigned short As[64 * 136];    // 17408 B
    const int m0 = blockIdx.x * 64;
    const int tid = threadIdx.x;

    for (int f = tid; f < 2048; f += 256) {          // whole Wout
        int r = f >> 4, c = f & 15;
        *(uint4*)&Ws[r * 136 + c * 8] = *(const uint4*)(woutb + (size_t)r * DM + c * 8);
    }
    for (int f = tid; f < 1024; f += 256) {          // A tile (zero pad beyond M)
        int t = f >> 4, c = f & 15;
        uint4 w = make_uint4(0u, 0u, 0u, 0u);
        if (m0 + t < M)
            w = *(const uint4*)(attn_b + (size_t)(m0 + t) * DM + c * 8);
        *(uint4*)&As[t * 136 + c * 8] = w;
    }
    __syncthreads();

    const int wave = tid >> 6, lane = tid & 63, quad = lane >> 4, l16 = lane & 15;
    const int mr = wave * 16;
    #pragma unroll
    for (int ct = 0; ct < 8; ++ct) {
        f32x4 acc = {0.f, 0.f, 0.f, 0.f};
        #pragma unroll
        for (int ks = 0; ks < 4; ++ks) {
            bf16x8 a = *(const bf16x8*)&As[(mr + l16) * 136 + ks * 32 + quad * 8];
            bf16x8 bb = *(const bf16x8*)&Ws[(ct * 16 + l16) * 136 + ks * 32 + quad * 8];
            acc = __builtin_amdgcn_mfma_f32_16x16x32_bf16(a, bb, acc, 0, 0, 0);
        }
        const int gc = ct * 16 + l16;
        const float bias = bout[gc];
        #pragma unroll
        for (int r = 0; r < 4; ++r) {
            int row = m0 + mr + quad * 4 + r;
            if (row < M)
                out[(size_t)row * DM + gc] = acc[r] + bias;
        }
    }
}

extern "C" void kernel_launch(void* const* d_in, const int* in_sizes, int n_in,
                              void* d_out, int out_size, void* d_ws, size_t ws_size,
                              hipStream_t stream) {
    const float* att_in     = (const float*)d_in[0];
    const float* in_proj_w  = (const float*)d_in[1];
    const float* in_proj_b  = (const float*)d_in[2];
    const float* out_proj_w = (const float*)d_in[3];
    const float* out_proj_b = (const float*)d_in[4];
    const int*   agents     = (const int*)d_in[5];
    const int B = in_sizes[5];
    const int M = out_size / DM;             // total tokens (66560)

    // ws layout (assumes ws_size >= ~17.2 MB):
    //   [0,8192)            offs
    //   [8192,106496)       wqkv bf16
    //   [106496,139264)     wout bf16
    //   [139264, +M*256)    Q bf16, later attn_out bf16 (overwritten in-place by attn)
    int* offs = (int*)d_ws;
    unsigned short* wqkv_bf = (unsigned short*)((char*)d_ws + 8192);
    unsigned short* wout_bf = (unsigned short*)((char*)d_ws + 106496);
    unsigned short* qbuf    = (unsigned short*)((char*)d_ws + 139264);
    unsigned short* kvbuf   = (unsigned short*)d_out;   // [M][256] bf16 == exactly out bytes

    hipLaunchKernelGGL(prep, dim3(65), dim3(256), 0, stream,
                       agents, B, in_proj_w, out_proj_w, offs, wqkv_bf, wout_bf);
    hipLaunchKernelGGL(qkv_gemm, dim3((M + 63) / 64, 6), dim3(256), 0, stream,
                       att_in, wqkv_bf, in_proj_b, qbuf, kvbuf, M);
    hipLaunchKernelGGL(attn, dim3(B), dim3(512), 0, stream,
                       qbuf, kvbuf, agents, offs);
    hipLaunchKernelGGL(oproj, dim3((M + 63) / 64), dim3(256), 0, stream,
                       qbuf, wout_bf, out_proj_b, (float*)d_out, M);
}